// Round 11
// baseline (181.033 us; speedup 1.0000x reference)
//
#include <hip/hip_runtime.h>

// ---------------------------------------------------------------------------
// GNN: 2x SAGEConv(mean) + ReLU, global mean pool, 2-layer MLP classifier.
// N=50000 nodes, E=600000 edges, F=H=128, 64 graphs. fp32 in/out.
// R2: hierarchical scan. R3: pool fused into linear epilogue.
// R4: gcnt via binary search. R5: linear -> MFMA bf16x3. R6: bf16 gather.
// R7: CSR via two-level counting sort. R8 (reverted): fusion killed TLP.
// R9: h1 bf16-only. R10: T bf16; dispatch diet.
// R11: (a) linear de-LDS'd: A/B fragments loaded straight from global
//         (B is fragment-linear + L2-hot; A rows bf16) -> no barriers, no
//         bank conflicts; x self-term bf16 (lo dropped; error ~= h1bf rounding).
//      (b) bscan_a folded into bscan_b (redundant per-block totals).
// ---------------------------------------------------------------------------

typedef __attribute__((ext_vector_type(8))) short bf16x8;
typedef __attribute__((ext_vector_type(8))) unsigned short ushort8;
typedef __attribute__((ext_vector_type(4))) float f32x4;

#define HBLK 4096  // edges per block in the bucket passes

__device__ inline unsigned short f2bf(float f) {
  unsigned u = __float_as_uint(f);
  u += 0x7fff + ((u >> 16) & 1);  // round-to-nearest-even
  return (unsigned short)(u >> 16);
}
__device__ inline float bf2f(unsigned short h) { return __uint_as_float(((unsigned)h) << 16); }

// ---- fused prep: tobf | wprep(W1) | wprep(W2) | hist | {gcnt + gsum=0} ----

__device__ inline void wprep_body(int id, const float* __restrict__ Wl, const float* __restrict__ Wr,
                                  unsigned short* __restrict__ Bpre) {
  // Bpre layout: [kk 8][half 2][ct 8][lane 64][j 8] bf16
  if (id >= 4096) return;
  int kk = id >> 9;
  int ct = (id >> 6) & 7;
  int l  = id & 63;
  int colIdx = ct * 16 + (l & 15);
  int k0 = kk * 32 + (l >> 4) * 8;
  const float* W = (k0 < 128) ? Wl : Wr;
  int kb = k0 & 127;
#pragma unroll
  for (int j = 0; j < 8; ++j) {
    float v = W[colIdx * 128 + kb + j];
    unsigned short h = f2bf(v);
    size_t bh = (size_t)kk * 8192 + ((size_t)ct * 64 + l) * 8 + j;
    Bpre[bh] = h;
    Bpre[bh + 4096] = f2bf(v - bf2f(h));
  }
}

__global__ __launch_bounds__(256) void k_prep(
    const float* __restrict__ x, unsigned short* __restrict__ xbf, int total,
    const float* __restrict__ W1l, const float* __restrict__ W1r, unsigned short* __restrict__ Bpre1,
    const float* __restrict__ W2l, const float* __restrict__ W2r, unsigned short* __restrict__ Bpre2,
    const int* __restrict__ batch, int* __restrict__ gcnt, float* __restrict__ gsum, int N,
    const int* __restrict__ ei, int* __restrict__ bhist, int E,
    int nTobf, int nEblk) {
  __shared__ int h[256];
  int b = blockIdx.x;
  int tid = threadIdx.x;
  if (b < nTobf) {
    int i = (b * 256 + tid) * 4;
    if (i + 3 < total) {
      float4 v = *(const float4*)(x + i);
      ushort4 p;
      p.x = f2bf(v.x); p.y = f2bf(v.y); p.z = f2bf(v.z); p.w = f2bf(v.w);
      *(ushort4*)(xbf + i) = p;
    } else {
      for (int k = 0; k < 4 && i + k < total; ++k) xbf[i + k] = f2bf(x[i + k]);
    }
  } else if (b < nTobf + 16) {
    wprep_body((b - nTobf) * 256 + tid, W1l, W1r, Bpre1);
  } else if (b < nTobf + 32) {
    wprep_body((b - nTobf - 16) * 256 + tid, W2l, W2r, Bpre2);
  } else if (b < nTobf + 32 + nEblk) {
    int eb = b - nTobf - 32;
    h[tid] = 0;
    __syncthreads();
    int base = eb * HBLK;
    int end = min(base + HBLK, E);
    for (int e = base + tid; e < end; e += 256) atomicAdd(&h[ei[E + e] >> 8], 1);
    __syncthreads();
    bhist[eb * 256 + tid] = h[tid];
  } else {
    for (int i = tid; i < 64 * 128; i += 256) gsum[i] = 0.f;
    if (tid < 64) {
      int g = tid;
      int lo = 0, hi = N;
      while (lo < hi) { int mid = (lo + hi) >> 1; if (batch[mid] < g) lo = mid + 1; else hi = mid; }
      int a = lo;
      lo = 0; hi = N;
      while (lo < hi) { int mid = (lo + hi) >> 1; if (batch[mid] < g + 1) lo = mid + 1; else hi = mid; }
      gcnt[g] = lo - a;
    }
  }
}

// ---- CSR build ------------------------------------------------------------
// k_bscan (one block per bucket, grid 256): redundantly computes all bucket
// totals (coalesced 1KB rows, L2-hot), scans them for this bucket's base,
// then scans the per-scat-block counts for this bucket -> cursors in bhist.

__global__ __launch_bounds__(256) void k_bscan(int* __restrict__ bhist, int* __restrict__ bukbase,
                                               int nblk) {
  __shared__ int s[256];
  int buk = blockIdx.x;
  int t = threadIdx.x;
  int sum = 0;
  for (int b = 0; b < nblk; ++b) sum += bhist[b * 256 + t];  // coalesced rows
  s[t] = sum;
  __syncthreads();
  for (int d = 1; d < 256; d <<= 1) {
    int v = (t >= d) ? s[t - d] : 0;
    __syncthreads();
    s[t] += v;
    __syncthreads();
  }
  int myBase = (buk == 0) ? 0 : s[buk - 1];
  int tot = s[255];
  __syncthreads();
  int c = (t < nblk) ? bhist[t * 256 + buk] : 0;
  s[t] = c;
  __syncthreads();
  for (int d = 1; d < 256; d <<= 1) {
    int v = (t >= d) ? s[t - d] : 0;
    __syncthreads();
    s[t] += v;
    __syncthreads();
  }
  if (t < nblk) bhist[t * 256 + buk] = myBase + s[t] - c;
  if (t == 0) bukbase[buk] = myBase;
  if (buk == 255 && t == 1) bukbase[256] = tot;
}

__global__ __launch_bounds__(256) void k_scat(const int* __restrict__ ei, const int* __restrict__ bhist,
                                              unsigned* __restrict__ ebuk, int E) {
  __shared__ int cur[256];
  int tid = threadIdx.x;
  cur[tid] = bhist[blockIdx.x * 256 + tid];
  __syncthreads();
  int base = blockIdx.x * HBLK;
  int end = min(base + HBLK, E);
  for (int e = base + tid; e < end; e += 256) {
    int d = ei[E + e];
    int srcv = ei[e];
    int p = atomicAdd(&cur[d >> 8], 1);
    ebuk[p] = ((unsigned)(d & 255) << 24) | (unsigned)srcv;
  }
}

__global__ __launch_bounds__(256) void k_bucket(const unsigned* __restrict__ ebuk,
                                                const int* __restrict__ bukbase,
                                                int* __restrict__ off, int* __restrict__ colv,
                                                int N, int E) {
  __shared__ int h[256];
  __shared__ int cur[256];
  __shared__ int sc[256];
  int tid = threadIdx.x;
  int buk = blockIdx.x;
  int b0 = bukbase[buk], b1 = bukbase[buk + 1];
  h[tid] = 0;
  __syncthreads();
  for (int i = b0 + tid; i < b1; i += 256) atomicAdd(&h[ebuk[i] >> 24], 1);
  __syncthreads();
  int my = h[tid];
  sc[tid] = my;
  __syncthreads();
  for (int d = 1; d < 256; d <<= 1) {
    int v = (tid >= d) ? sc[tid - d] : 0;
    __syncthreads();
    sc[tid] += v;
    __syncthreads();
  }
  int excl = sc[tid] - my;
  cur[tid] = excl;
  int node = buk * 256 + tid;
  if (node < N) off[node] = b0 + excl;
  if (buk == gridDim.x - 1 && tid == 0) off[N] = E;
  __syncthreads();
  for (int i = b0 + tid; i < b1; i += 256) {
    unsigned v = ebuk[i];
    int p = atomicAdd(&cur[v >> 24], 1);
    colv[b0 + p] = (int)(v & 0xFFFFFFu);
  }
}

// ---- mean aggregation (bf16 source -> bf16 output) ------------------------

__global__ __launch_bounds__(256) void k_agg_bf(const unsigned short* __restrict__ Xbf,
                                                const int* __restrict__ off, const int* __restrict__ col,
                                                unsigned short* __restrict__ Tbf, int N) {
  int wid = (blockIdx.x * 256 + threadIdx.x) >> 6;
  int ln = threadIdx.x & 63;
  if (wid >= N) return;
  int o0 = off[wid], o1 = off[wid + 1];
  int deg = o1 - o0;
  int rs = ln >> 4, fs = ln & 15;
  float acc[8];
#pragma unroll
  for (int j = 0; j < 8; ++j) acc[j] = 0.f;

  for (int base = 0; base < deg; base += 16) {
#pragma unroll
    for (int u = 0; u < 4; ++u) {
      int n = base + u * 4 + rs;
      if (n < deg) {
        int idx = col[o0 + n];
        ushort8 q = *(const ushort8*)(Xbf + (size_t)idx * 128 + fs * 8);
#pragma unroll
        for (int j = 0; j < 8; ++j) acc[j] += bf2f(q[j]);
      }
    }
  }
#pragma unroll
  for (int j = 0; j < 8; ++j) {
    acc[j] += __shfl_xor(acc[j], 16);
    acc[j] += __shfl_xor(acc[j], 32);
  }
  if (rs == 0) {
    float sc = 1.0f / (float)max(deg, 1);
    unsigned short w[8];
#pragma unroll
    for (int j = 0; j < 8; ++j) w[j] = f2bf(acc[j] * sc);
    uint4 uw;
    uw.x = (unsigned)w[0] | ((unsigned)w[1] << 16);
    uw.y = (unsigned)w[2] | ((unsigned)w[3] << 16);
    uw.z = (unsigned)w[4] | ((unsigned)w[5] << 16);
    uw.w = (unsigned)w[6] | ((unsigned)w[7] << 16);
    *(uint4*)(Tbf + (size_t)wid * 128 + fs * 8) = uw;
  }
}

// ---- MFMA linear, register-direct: H = relu([T|X] @ [Wl;Wr].T + b) --------
// No LDS staging: A fragments read straight from row-major bf16 global
// (lane ln, rowgroup rg -> row rg*16+(ln&15), k-chunk (ln>>4)*8); B fragments
// from fragment-linear Bpre (L2-hot, coalesced). 4 MFMA/kk (A-hi x B-hi/lo,
// two col-tiles). mode 0: write OUTbf. mode 1: pool into gsum.

__global__ __launch_bounds__(256) void k_lin2(
    const unsigned short* __restrict__ Agg,   // Tbf [N][128]
    const unsigned short* __restrict__ Self,  // xbf or h1bf [N][128]
    const unsigned short* __restrict__ Bpre,
    const float* __restrict__ bias,
    unsigned short* __restrict__ OUTbf,
    const int* __restrict__ batch, float* __restrict__ gsum,
    int N, int mode) {
  __shared__ float ps[128];
  int tid = threadIdx.x;
  int wv = tid >> 6, ln = tid & 63;
  int rowBase = blockIdx.x * 64;
  int kq = (ln >> 4) * 8;   // k-chunk within 32
  int rsel = ln & 15;       // row within 16
  int c0 = wv * 2;

  f32x4 acc[4][2];
#pragma unroll
  for (int rg = 0; rg < 4; ++rg) {
    acc[rg][0] = (f32x4){0.f, 0.f, 0.f, 0.f};
    acc[rg][1] = (f32x4){0.f, 0.f, 0.f, 0.f};
  }

#pragma unroll
  for (int kk = 0; kk < 8; ++kk) {
    const unsigned short* S = (kk < 4) ? Agg : Self;
    int kOff = (kk & 3) * 32 + kq;
    const unsigned short* Bk = Bpre + (size_t)kk * 8192;
    bf16x8 bh0 = *(const bf16x8*)(Bk + ((size_t)c0 * 64 + ln) * 8);
    bf16x8 bl0 = *(const bf16x8*)(Bk + 4096 + ((size_t)c0 * 64 + ln) * 8);
    bf16x8 bh1 = *(const bf16x8*)(Bk + ((size_t)(c0 + 1) * 64 + ln) * 8);
    bf16x8 bl1 = *(const bf16x8*)(Bk + 4096 + ((size_t)(c0 + 1) * 64 + ln) * 8);
    bf16x8 ah[4];
#pragma unroll
    for (int rg = 0; rg < 4; ++rg) {
      int row = min(rowBase + rg * 16 + rsel, N - 1);
      ah[rg] = *(const bf16x8*)(S + (size_t)row * 128 + kOff);
    }
#pragma unroll
    for (int rg = 0; rg < 4; ++rg) {
      acc[rg][0] = __builtin_amdgcn_mfma_f32_16x16x32_bf16(ah[rg], bh0, acc[rg][0], 0, 0, 0);
      acc[rg][0] = __builtin_amdgcn_mfma_f32_16x16x32_bf16(ah[rg], bl0, acc[rg][0], 0, 0, 0);
      acc[rg][1] = __builtin_amdgcn_mfma_f32_16x16x32_bf16(ah[rg], bh1, acc[rg][1], 0, 0, 0);
      acc[rg][1] = __builtin_amdgcn_mfma_f32_16x16x32_bf16(ah[rg], bl1, acc[rg][1], 0, 0, 0);
    }
  }

  // epilogue: bias + relu. C layout: col=lane&15, row=(lane>>4)*4+reg (m89).
  int lcol = ln & 15;
  int rsub = (ln >> 4) * 4;
#pragma unroll
  for (int c = 0; c < 2; ++c) {
    float b = bias[(wv * 2 + c) * 16 + lcol];
#pragma unroll
    for (int rg = 0; rg < 4; ++rg)
#pragma unroll
      for (int r = 0; r < 4; ++r) acc[rg][c][r] = fmaxf(acc[rg][c][r] + b, 0.f);
  }

  if (mode == 0) {
#pragma unroll
    for (int rg = 0; rg < 4; ++rg)
#pragma unroll
      for (int r = 0; r < 4; ++r) {
        int row = rowBase + rg * 16 + rsub + r;
        if (row < N) {
          OUTbf[(size_t)row * 128 + (wv * 2 + 0) * 16 + lcol] = f2bf(acc[rg][0][r]);
          OUTbf[(size_t)row * 128 + (wv * 2 + 1) * 16 + lcol] = f2bf(acc[rg][1][r]);
        }
      }
  } else {
    if (tid < 128) ps[tid] = 0.f;
    __syncthreads();
    int lastRow = min(rowBase + 63, N - 1);
    int g0 = batch[rowBase], g1 = batch[lastRow];
    if (g0 == g1) {
#pragma unroll
      for (int c = 0; c < 2; ++c) {
        float s = 0.f;
#pragma unroll
        for (int rg = 0; rg < 4; ++rg)
#pragma unroll
          for (int r = 0; r < 4; ++r) {
            int row = rowBase + rg * 16 + rsub + r;
            if (row < N) s += acc[rg][c][r];
          }
        atomicAdd(&ps[(wv * 2 + c) * 16 + lcol], s);
      }
      __syncthreads();
      if (tid < 128) atomicAdd(&gsum[g0 * 128 + tid], ps[tid]);
    } else {
#pragma unroll
      for (int rg = 0; rg < 4; ++rg)
#pragma unroll
        for (int r = 0; r < 4; ++r) {
          int row = rowBase + rg * 16 + rsub + r;
          if (row < N) {
            int g = batch[row];
            atomicAdd(&gsum[g * 128 + (wv * 2 + 0) * 16 + lcol], acc[rg][0][r]);
            atomicAdd(&gsum[g * 128 + (wv * 2 + 1) * 16 + lcol], acc[rg][1][r]);
          }
        }
    }
  }
}

// ---- fused classifier -----------------------------------------------------

__global__ __launch_bounds__(128) void k_cls(const float* __restrict__ gsum, const int* __restrict__ gcnt,
                                             const float* __restrict__ Wc1, const float* __restrict__ bc1,
                                             const float* __restrict__ Wc2, const float* __restrict__ bc2,
                                             float* __restrict__ out) {
  __shared__ float red[128];
  int g = blockIdx.x;
  int h = threadIdx.x;
  float inv = 1.0f / (float)max(gcnt[g], 1);
  float s = 0.f;
  for (int f = 0; f < 128; ++f) s += gsum[g * 128 + f] * Wc1[h * 128 + f];
  red[h] = fmaxf(s * inv + bc1[h], 0.f) * Wc2[h];
  __syncthreads();
  for (int d = 64; d > 0; d >>= 1) {
    if (h < d) red[h] += red[h + d];
    __syncthreads();
  }
  if (h == 0) out[g] = red[0] + bc2[0];
}

// ---------------------------------------------------------------------------

extern "C" void kernel_launch(void* const* d_in, const int* in_sizes, int n_in,
                              void* d_out, int out_size, void* d_ws, size_t ws_size,
                              hipStream_t stream) {
  const float* x   = (const float*)d_in[0];
  const int*   ei  = (const int*)d_in[1];
  const int*   bat = (const int*)d_in[2];
  const float* W1l = (const float*)d_in[3];
  const float* b1l = (const float*)d_in[4];
  const float* W1r = (const float*)d_in[5];
  const float* W2l = (const float*)d_in[6];
  const float* b2l = (const float*)d_in[7];
  const float* W2r = (const float*)d_in[8];
  const float* Wc1 = (const float*)d_in[9];
  const float* bc1 = (const float*)d_in[10];
  const float* Wc2 = (const float*)d_in[11];
  const float* bc2 = (const float*)d_in[12];
  float* out = (float*)d_out;

  int N = in_sizes[0] / 128;
  int E = in_sizes[1] / 2;
  int nEblk = (E + HBLK - 1) / HBLK;       // 147
  int nBuk = (N + 255) >> 8;               // 196
  int total = N * 128;
  int nTobf = (total / 4 + 255) / 256;     // 6250

  char* ws = (char*)d_ws;
  size_t o = 0;
  auto alloc = [&](size_t bytes) {
    char* p = ws + o;
    o += (bytes + 255) & ~(size_t)255;
    return p;
  };
  int*      off    = (int*)alloc((size_t)(N + 1) * 4);
  int*      col    = (int*)alloc((size_t)E * 4);
  unsigned* ebuk   = (unsigned*)alloc((size_t)E * 4);
  int*      bhist  = (int*)alloc((size_t)nEblk * 256 * 4);
  int*      bukbase= (int*)alloc(257 * 4);
  unsigned short* Tbf  = (unsigned short*)alloc((size_t)N * 128 * 2);
  unsigned short* xbf  = (unsigned short*)alloc((size_t)N * 128 * 2);
  unsigned short* h1bf = (unsigned short*)alloc((size_t)N * 128 * 2);
  unsigned short* Bpre1 = (unsigned short*)alloc(65536 * 2);
  unsigned short* Bpre2 = (unsigned short*)alloc(65536 * 2);
  float*    gsum   = (float*)alloc(64 * 128 * 4 + 64 * 4);
  int*      gcnt   = (int*)(gsum + 64 * 128);

  // fused prep (tobf | wprep1 | wprep2 | hist | gcnt+gsum0)
  k_prep<<<nTobf + 32 + nEblk + 1, 256, 0, stream>>>(
      x, xbf, total, W1l, W1r, Bpre1, W2l, W2r, Bpre2,
      bat, gcnt, gsum, N, ei, bhist, E, nTobf, nEblk);

  // CSR build
  k_bscan<<<256, 256, 0, stream>>>(bhist, bukbase, nEblk);
  k_scat<<<nEblk, 256, 0, stream>>>(ei, bhist, ebuk, E);
  k_bucket<<<nBuk, 256, 0, stream>>>(ebuk, bukbase, off, col, N, E);

  int nLinBlk = (N + 63) / 64;
  // layer 1: agg(xbf) -> Tbf; lin(Tbf, xbf) -> h1bf
  k_agg_bf<<<(N + 3) / 4, 256, 0, stream>>>(xbf, off, col, Tbf, N);
  k_lin2<<<nLinBlk, 256, 0, stream>>>(Tbf, xbf, Bpre1, b1l, h1bf, bat, gsum, N, 0);
  // layer 2: agg(h1bf) -> Tbf; lin(Tbf, h1bf) -> pooled gsum
  k_agg_bf<<<(N + 3) / 4, 256, 0, stream>>>(h1bf, off, col, Tbf, N);
  k_lin2<<<nLinBlk, 256, 0, stream>>>(Tbf, h1bf, Bpre2, b2l, nullptr, bat, gsum, N, 1);

  // classifier
  k_cls<<<64, 128, 0, stream>>>(gsum, gcnt, Wc1, bc1, Wc2, bc2, out);
}

// Round 12
// 163.555 us; speedup vs baseline: 1.1069x; 1.1069x over previous
//
#include <hip/hip_runtime.h>

// ---------------------------------------------------------------------------
// GNN: 2x SAGEConv(mean) + ReLU, global mean pool, 2-layer MLP classifier.
// N=50000 nodes, E=600000 edges, F=H=128, 64 graphs. fp32 in/out.
// R2: hierarchical scan. R3: pool fused into linear epilogue.
// R4: gcnt via binary search. R5: linear -> MFMA bf16x3. R6: bf16 gather.
// R7: CSR via two-level counting sort. R8 (reverted): fusion killed TLP.
// R9: h1 bf16-only. R10: T bf16; dispatch diet.
// R11 (partially reverted): register-direct lin lost to LDS+barriers
//     (MFMA chains stalled on L2 latency, compiler couldn't pipeline).
// R12: back to LDS-staged lin; kept merged k_bscan + all-bf16 A sources
//     (As hi-only, uniform 4 MFMA/kk; absmax 1.2e-4 validated in R11).
// ---------------------------------------------------------------------------

typedef __attribute__((ext_vector_type(8))) short bf16x8;
typedef __attribute__((ext_vector_type(8))) unsigned short ushort8;
typedef __attribute__((ext_vector_type(4))) float f32x4;

#define HBLK 4096  // edges per block in the bucket passes

__device__ inline unsigned short f2bf(float f) {
  unsigned u = __float_as_uint(f);
  u += 0x7fff + ((u >> 16) & 1);  // round-to-nearest-even
  return (unsigned short)(u >> 16);
}
__device__ inline float bf2f(unsigned short h) { return __uint_as_float(((unsigned)h) << 16); }

// ---- fused prep: tobf | wprep(W1) | wprep(W2) | hist | {gcnt + gsum=0} ----

__device__ inline void wprep_body(int id, const float* __restrict__ Wl, const float* __restrict__ Wr,
                                  unsigned short* __restrict__ Bpre) {
  // Bpre layout: [kk 8][half 2][ct 8][lane 64][j 8] bf16
  if (id >= 4096) return;
  int kk = id >> 9;
  int ct = (id >> 6) & 7;
  int l  = id & 63;
  int colIdx = ct * 16 + (l & 15);
  int k0 = kk * 32 + (l >> 4) * 8;
  const float* W = (k0 < 128) ? Wl : Wr;
  int kb = k0 & 127;
#pragma unroll
  for (int j = 0; j < 8; ++j) {
    float v = W[colIdx * 128 + kb + j];
    unsigned short h = f2bf(v);
    size_t bh = (size_t)kk * 8192 + ((size_t)ct * 64 + l) * 8 + j;
    Bpre[bh] = h;
    Bpre[bh + 4096] = f2bf(v - bf2f(h));
  }
}

__global__ __launch_bounds__(256) void k_prep(
    const float* __restrict__ x, unsigned short* __restrict__ xbf, int total,
    const float* __restrict__ W1l, const float* __restrict__ W1r, unsigned short* __restrict__ Bpre1,
    const float* __restrict__ W2l, const float* __restrict__ W2r, unsigned short* __restrict__ Bpre2,
    const int* __restrict__ batch, int* __restrict__ gcnt, float* __restrict__ gsum, int N,
    const int* __restrict__ ei, int* __restrict__ bhist, int E,
    int nTobf, int nEblk) {
  __shared__ int h[256];
  int b = blockIdx.x;
  int tid = threadIdx.x;
  if (b < nTobf) {
    int i = (b * 256 + tid) * 4;
    if (i + 3 < total) {
      float4 v = *(const float4*)(x + i);
      ushort4 p;
      p.x = f2bf(v.x); p.y = f2bf(v.y); p.z = f2bf(v.z); p.w = f2bf(v.w);
      *(ushort4*)(xbf + i) = p;
    } else {
      for (int k = 0; k < 4 && i + k < total; ++k) xbf[i + k] = f2bf(x[i + k]);
    }
  } else if (b < nTobf + 16) {
    wprep_body((b - nTobf) * 256 + tid, W1l, W1r, Bpre1);
  } else if (b < nTobf + 32) {
    wprep_body((b - nTobf - 16) * 256 + tid, W2l, W2r, Bpre2);
  } else if (b < nTobf + 32 + nEblk) {
    int eb = b - nTobf - 32;
    h[tid] = 0;
    __syncthreads();
    int base = eb * HBLK;
    int end = min(base + HBLK, E);
    for (int e = base + tid; e < end; e += 256) atomicAdd(&h[ei[E + e] >> 8], 1);
    __syncthreads();
    bhist[eb * 256 + tid] = h[tid];
  } else {
    for (int i = tid; i < 64 * 128; i += 256) gsum[i] = 0.f;
    if (tid < 64) {
      int g = tid;
      int lo = 0, hi = N;
      while (lo < hi) { int mid = (lo + hi) >> 1; if (batch[mid] < g) lo = mid + 1; else hi = mid; }
      int a = lo;
      lo = 0; hi = N;
      while (lo < hi) { int mid = (lo + hi) >> 1; if (batch[mid] < g + 1) lo = mid + 1; else hi = mid; }
      gcnt[g] = lo - a;
    }
  }
}

// ---- CSR build ------------------------------------------------------------
// k_bscan (one block per bucket): redundantly computes bucket totals
// (coalesced, L2-hot), scans for this bucket's base, then scans this
// bucket's per-scat-block counts -> cursors in bhist.

__global__ __launch_bounds__(256) void k_bscan(int* __restrict__ bhist, int* __restrict__ bukbase,
                                               int nblk) {
  __shared__ int s[256];
  int buk = blockIdx.x;
  int t = threadIdx.x;
  int sum = 0;
  for (int b = 0; b < nblk; ++b) sum += bhist[b * 256 + t];
  s[t] = sum;
  __syncthreads();
  for (int d = 1; d < 256; d <<= 1) {
    int v = (t >= d) ? s[t - d] : 0;
    __syncthreads();
    s[t] += v;
    __syncthreads();
  }
  int myBase = (buk == 0) ? 0 : s[buk - 1];
  int tot = s[255];
  __syncthreads();
  int c = (t < nblk) ? bhist[t * 256 + buk] : 0;
  s[t] = c;
  __syncthreads();
  for (int d = 1; d < 256; d <<= 1) {
    int v = (t >= d) ? s[t - d] : 0;
    __syncthreads();
    s[t] += v;
    __syncthreads();
  }
  if (t < nblk) bhist[t * 256 + buk] = myBase + s[t] - c;
  if (t == 0) bukbase[buk] = myBase;
  if (buk == 255 && t == 1) bukbase[256] = tot;
}

__global__ __launch_bounds__(256) void k_scat(const int* __restrict__ ei, const int* __restrict__ bhist,
                                              unsigned* __restrict__ ebuk, int E) {
  __shared__ int cur[256];
  int tid = threadIdx.x;
  cur[tid] = bhist[blockIdx.x * 256 + tid];
  __syncthreads();
  int base = blockIdx.x * HBLK;
  int end = min(base + HBLK, E);
  for (int e = base + tid; e < end; e += 256) {
    int d = ei[E + e];
    int srcv = ei[e];
    int p = atomicAdd(&cur[d >> 8], 1);
    ebuk[p] = ((unsigned)(d & 255) << 24) | (unsigned)srcv;
  }
}

__global__ __launch_bounds__(256) void k_bucket(const unsigned* __restrict__ ebuk,
                                                const int* __restrict__ bukbase,
                                                int* __restrict__ off, int* __restrict__ colv,
                                                int N, int E) {
  __shared__ int h[256];
  __shared__ int cur[256];
  __shared__ int sc[256];
  int tid = threadIdx.x;
  int buk = blockIdx.x;
  int b0 = bukbase[buk], b1 = bukbase[buk + 1];
  h[tid] = 0;
  __syncthreads();
  for (int i = b0 + tid; i < b1; i += 256) atomicAdd(&h[ebuk[i] >> 24], 1);
  __syncthreads();
  int my = h[tid];
  sc[tid] = my;
  __syncthreads();
  for (int d = 1; d < 256; d <<= 1) {
    int v = (tid >= d) ? sc[tid - d] : 0;
    __syncthreads();
    sc[tid] += v;
    __syncthreads();
  }
  int excl = sc[tid] - my;
  cur[tid] = excl;
  int node = buk * 256 + tid;
  if (node < N) off[node] = b0 + excl;
  if (buk == gridDim.x - 1 && tid == 0) off[N] = E;
  __syncthreads();
  for (int i = b0 + tid; i < b1; i += 256) {
    unsigned v = ebuk[i];
    int p = atomicAdd(&cur[v >> 24], 1);
    colv[b0 + p] = (int)(v & 0xFFFFFFu);
  }
}

// ---- mean aggregation (bf16 source -> bf16 output) ------------------------

__global__ __launch_bounds__(256) void k_agg_bf(const unsigned short* __restrict__ Xbf,
                                                const int* __restrict__ off, const int* __restrict__ col,
                                                unsigned short* __restrict__ Tbf, int N) {
  int wid = (blockIdx.x * 256 + threadIdx.x) >> 6;
  int ln = threadIdx.x & 63;
  if (wid >= N) return;
  int o0 = off[wid], o1 = off[wid + 1];
  int deg = o1 - o0;
  int rs = ln >> 4, fs = ln & 15;
  float acc[8];
#pragma unroll
  for (int j = 0; j < 8; ++j) acc[j] = 0.f;

  for (int base = 0; base < deg; base += 16) {
#pragma unroll
    for (int u = 0; u < 4; ++u) {
      int n = base + u * 4 + rs;
      if (n < deg) {
        int idx = col[o0 + n];
        ushort8 q = *(const ushort8*)(Xbf + (size_t)idx * 128 + fs * 8);
#pragma unroll
        for (int j = 0; j < 8; ++j) acc[j] += bf2f(q[j]);
      }
    }
  }
#pragma unroll
  for (int j = 0; j < 8; ++j) {
    acc[j] += __shfl_xor(acc[j], 16);
    acc[j] += __shfl_xor(acc[j], 32);
  }
  if (rs == 0) {
    float sc = 1.0f / (float)max(deg, 1);
    unsigned short w[8];
#pragma unroll
    for (int j = 0; j < 8; ++j) w[j] = f2bf(acc[j] * sc);
    uint4 uw;
    uw.x = (unsigned)w[0] | ((unsigned)w[1] << 16);
    uw.y = (unsigned)w[2] | ((unsigned)w[3] << 16);
    uw.z = (unsigned)w[4] | ((unsigned)w[5] << 16);
    uw.w = (unsigned)w[6] | ((unsigned)w[7] << 16);
    *(uint4*)(Tbf + (size_t)wid * 128 + fs * 8) = uw;
  }
}

// ---- MFMA linear (LDS-staged): H = relu([T|X] @ [Wl;Wr].T + b) ------------
// All A sources bf16 (hi only, 4 MFMA/kk). B hi/lo from fragment-linear Bpre.
// mode 0: write OUTbf (h1 bf16). mode 1: pool into gsum (batch sorted).

__global__ __launch_bounds__(256) void k_lin_mfma(
    const unsigned short* __restrict__ Agg,   // Tbf [N][128]
    const unsigned short* __restrict__ Self,  // xbf or h1bf [N][128]
    const unsigned short* __restrict__ Bpre,
    const float* __restrict__ bias,
    unsigned short* __restrict__ OUTbf,
    const int* __restrict__ batch, float* __restrict__ gsum,
    int N, int mode) {
  __shared__ unsigned short As[2048];  // [rowgrp 4][lane 64][8]  4KB (hi only)
  __shared__ unsigned short Bs[8192];  // [half 2][ct 8][lane 64][8] 16KB
  __shared__ float ps[128];

  int tid = threadIdx.x;
  int wv = tid >> 6, ln = tid & 63;
  int rowBase = blockIdx.x * 64;

  int sRow = tid >> 2;
  int sKq = tid & 3;
  int sgr = min(rowBase + sRow, N - 1);
  int sSlot = ((sRow >> 4) * 64 + (sKq << 4) + (sRow & 15)) * 8;  // shorts

  f32x4 acc[4][2];
#pragma unroll
  for (int rg = 0; rg < 4; ++rg) {
    acc[rg][0] = (f32x4){0.f, 0.f, 0.f, 0.f};
    acc[rg][1] = (f32x4){0.f, 0.f, 0.f, 0.f};
  }

  const uint4* BpreV = (const uint4*)Bpre;

  for (int kk = 0; kk < 8; ++kk) {
    const unsigned short* S = (kk < 4) ? Agg : Self;
    int kOff = (kk & 3) * 32 + sKq * 8;
    // issue all global loads before the barrier (independent batch)
    uint4 ua = *(const uint4*)(S + (size_t)sgr * 128 + kOff);
    uint4 b0 = BpreV[kk * 1024 + tid];
    uint4 b1 = BpreV[kk * 1024 + tid + 256];
    uint4 b2 = BpreV[kk * 1024 + tid + 512];
    uint4 b3 = BpreV[kk * 1024 + tid + 768];

    __syncthreads();  // previous iteration's reads done
    *(uint4*)(As + sSlot) = ua;
    uint4* BsV = (uint4*)Bs;
    BsV[tid] = b0;
    BsV[tid + 256] = b1;
    BsV[tid + 512] = b2;
    BsV[tid + 768] = b3;
    __syncthreads();

    int c0 = wv * 2;
    bf16x8 bh0 = *(bf16x8*)(Bs + ((size_t)c0 * 64 + ln) * 8);
    bf16x8 bl0 = *(bf16x8*)(Bs + 4096 + ((size_t)c0 * 64 + ln) * 8);
    bf16x8 bh1 = *(bf16x8*)(Bs + ((size_t)(c0 + 1) * 64 + ln) * 8);
    bf16x8 bl1 = *(bf16x8*)(Bs + 4096 + ((size_t)(c0 + 1) * 64 + ln) * 8);
#pragma unroll
    for (int rg = 0; rg < 4; ++rg) {
      bf16x8 ah = *(bf16x8*)(As + ((size_t)rg * 64 + ln) * 8);
      acc[rg][0] = __builtin_amdgcn_mfma_f32_16x16x32_bf16(ah, bh0, acc[rg][0], 0, 0, 0);
      acc[rg][0] = __builtin_amdgcn_mfma_f32_16x16x32_bf16(ah, bl0, acc[rg][0], 0, 0, 0);
      acc[rg][1] = __builtin_amdgcn_mfma_f32_16x16x32_bf16(ah, bh1, acc[rg][1], 0, 0, 0);
      acc[rg][1] = __builtin_amdgcn_mfma_f32_16x16x32_bf16(ah, bl1, acc[rg][1], 0, 0, 0);
    }
  }

  // epilogue: bias + relu. C layout: col=lane&15, row=(lane>>4)*4+reg (m89).
  int lcol = ln & 15;
  int rsub = (ln >> 4) * 4;
#pragma unroll
  for (int c = 0; c < 2; ++c) {
    float b = bias[(wv * 2 + c) * 16 + lcol];
#pragma unroll
    for (int rg = 0; rg < 4; ++rg)
#pragma unroll
      for (int r = 0; r < 4; ++r) acc[rg][c][r] = fmaxf(acc[rg][c][r] + b, 0.f);
  }

  if (mode == 0) {
#pragma unroll
    for (int rg = 0; rg < 4; ++rg)
#pragma unroll
      for (int r = 0; r < 4; ++r) {
        int row = rowBase + rg * 16 + rsub + r;
        if (row < N) {
          OUTbf[(size_t)row * 128 + (wv * 2 + 0) * 16 + lcol] = f2bf(acc[rg][0][r]);
          OUTbf[(size_t)row * 128 + (wv * 2 + 1) * 16 + lcol] = f2bf(acc[rg][1][r]);
        }
      }
  } else {
    if (tid < 128) ps[tid] = 0.f;
    __syncthreads();
    int lastRow = min(rowBase + 63, N - 1);
    int g0 = batch[rowBase], g1 = batch[lastRow];
    if (g0 == g1) {
#pragma unroll
      for (int c = 0; c < 2; ++c) {
        float s = 0.f;
#pragma unroll
        for (int rg = 0; rg < 4; ++rg)
#pragma unroll
          for (int r = 0; r < 4; ++r) {
            int row = rowBase + rg * 16 + rsub + r;
            if (row < N) s += acc[rg][c][r];
          }
        atomicAdd(&ps[(wv * 2 + c) * 16 + lcol], s);
      }
      __syncthreads();
      if (tid < 128) atomicAdd(&gsum[g0 * 128 + tid], ps[tid]);
    } else {
#pragma unroll
      for (int rg = 0; rg < 4; ++rg)
#pragma unroll
        for (int r = 0; r < 4; ++r) {
          int row = rowBase + rg * 16 + rsub + r;
          if (row < N) {
            int g = batch[row];
            atomicAdd(&gsum[g * 128 + (wv * 2 + 0) * 16 + lcol], acc[rg][0][r]);
            atomicAdd(&gsum[g * 128 + (wv * 2 + 1) * 16 + lcol], acc[rg][1][r]);
          }
        }
    }
  }
}

// ---- fused classifier -----------------------------------------------------

__global__ __launch_bounds__(128) void k_cls(const float* __restrict__ gsum, const int* __restrict__ gcnt,
                                             const float* __restrict__ Wc1, const float* __restrict__ bc1,
                                             const float* __restrict__ Wc2, const float* __restrict__ bc2,
                                             float* __restrict__ out) {
  __shared__ float red[128];
  int g = blockIdx.x;
  int h = threadIdx.x;
  float inv = 1.0f / (float)max(gcnt[g], 1);
  float s = 0.f;
  for (int f = 0; f < 128; ++f) s += gsum[g * 128 + f] * Wc1[h * 128 + f];
  red[h] = fmaxf(s * inv + bc1[h], 0.f) * Wc2[h];
  __syncthreads();
  for (int d = 64; d > 0; d >>= 1) {
    if (h < d) red[h] += red[h + d];
    __syncthreads();
  }
  if (h == 0) out[g] = red[0] + bc2[0];
}

// ---------------------------------------------------------------------------

extern "C" void kernel_launch(void* const* d_in, const int* in_sizes, int n_in,
                              void* d_out, int out_size, void* d_ws, size_t ws_size,
                              hipStream_t stream) {
  const float* x   = (const float*)d_in[0];
  const int*   ei  = (const int*)d_in[1];
  const int*   bat = (const int*)d_in[2];
  const float* W1l = (const float*)d_in[3];
  const float* b1l = (const float*)d_in[4];
  const float* W1r = (const float*)d_in[5];
  const float* W2l = (const float*)d_in[6];
  const float* b2l = (const float*)d_in[7];
  const float* W2r = (const float*)d_in[8];
  const float* Wc1 = (const float*)d_in[9];
  const float* bc1 = (const float*)d_in[10];
  const float* Wc2 = (const float*)d_in[11];
  const float* bc2 = (const float*)d_in[12];
  float* out = (float*)d_out;

  int N = in_sizes[0] / 128;
  int E = in_sizes[1] / 2;
  int nEblk = (E + HBLK - 1) / HBLK;       // 147
  int nBuk = (N + 255) >> 8;               // 196
  int total = N * 128;
  int nTobf = (total / 4 + 255) / 256;     // 6250

  char* ws = (char*)d_ws;
  size_t o = 0;
  auto alloc = [&](size_t bytes) {
    char* p = ws + o;
    o += (bytes + 255) & ~(size_t)255;
    return p;
  };
  int*      off    = (int*)alloc((size_t)(N + 1) * 4);
  int*      col    = (int*)alloc((size_t)E * 4);
  unsigned* ebuk   = (unsigned*)alloc((size_t)E * 4);
  int*      bhist  = (int*)alloc((size_t)nEblk * 256 * 4);
  int*      bukbase= (int*)alloc(257 * 4);
  unsigned short* Tbf  = (unsigned short*)alloc((size_t)N * 128 * 2);
  unsigned short* xbf  = (unsigned short*)alloc((size_t)N * 128 * 2);
  unsigned short* h1bf = (unsigned short*)alloc((size_t)N * 128 * 2);
  unsigned short* Bpre1 = (unsigned short*)alloc(65536 * 2);
  unsigned short* Bpre2 = (unsigned short*)alloc(65536 * 2);
  float*    gsum   = (float*)alloc(64 * 128 * 4 + 64 * 4);
  int*      gcnt   = (int*)(gsum + 64 * 128);

  // fused prep (tobf | wprep1 | wprep2 | hist | gcnt+gsum0)
  k_prep<<<nTobf + 32 + nEblk + 1, 256, 0, stream>>>(
      x, xbf, total, W1l, W1r, Bpre1, W2l, W2r, Bpre2,
      bat, gcnt, gsum, N, ei, bhist, E, nTobf, nEblk);

  // CSR build
  k_bscan<<<256, 256, 0, stream>>>(bhist, bukbase, nEblk);
  k_scat<<<nEblk, 256, 0, stream>>>(ei, bhist, ebuk, E);
  k_bucket<<<nBuk, 256, 0, stream>>>(ebuk, bukbase, off, col, N, E);

  int nLinBlk = (N + 63) / 64;
  // layer 1: agg(xbf) -> Tbf; lin(Tbf, xbf) -> h1bf
  k_agg_bf<<<(N + 3) / 4, 256, 0, stream>>>(xbf, off, col, Tbf, N);
  k_lin_mfma<<<nLinBlk, 256, 0, stream>>>(Tbf, xbf, Bpre1, b1l, h1bf, bat, gsum, N, 0);
  // layer 2: agg(h1bf) -> Tbf; lin(Tbf, h1bf) -> pooled gsum
  k_agg_bf<<<(N + 3) / 4, 256, 0, stream>>>(h1bf, off, col, Tbf, N);
  k_lin_mfma<<<nLinBlk, 256, 0, stream>>>(Tbf, h1bf, Bpre2, b2l, nullptr, bat, gsum, N, 1);

  // classifier
  k_cls<<<64, 128, 0, stream>>>(gsum, gcnt, Wc1, bc1, Wc2, bc2, out);
}